// Round 11
// baseline (361.438 us; speedup 1.0000x reference)
//
#include <hip/hip_runtime.h>

#define LR 0.01f

// Problem constants (from reference setup_inputs): B=4, S=2048, D=1024, Ds=256
constexpr int Bc  = 4;
constexpr int Sc  = 2048;
constexpr int Dc  = 1024;
constexpr int Dsc = 256;

// ---------------------------------------------------------------------------
// Tiled fp32 GEMM (v10, verified): A-tile transposed in LDS, float4 reads,
// float4 epilogue.
// ---------------------------------------------------------------------------
__global__ __launch_bounds__(256) void gemm_bias(
    const float* __restrict__ A, const float* __restrict__ Bm,
    const float* __restrict__ bias, const float* __restrict__ resid,
    float* __restrict__ C, int M, int N, int K) {
  constexpr int BM = 64, BN = 64, BK = 16;
  __shared__ float As[BM][BK + 4];
  __shared__ float Bs[BK][BN + 4];

  const int bm = blockIdx.x * BM;
  const int bn = blockIdx.y * BN;
  const int tx = threadIdx.x & 15;
  const int ty = threadIdx.x >> 4;

  float acc[4][4] = {};

  for (int k0 = 0; k0 < K; k0 += BK) {
#pragma unroll
    for (int qq = 0; qq < 4; ++qq) {
      int m = ty + 16 * qq;
      As[m][tx] = A[(size_t)(bm + m) * K + k0 + tx];
    }
#pragma unroll
    for (int qq = 0; qq < 4; ++qq) {
      int i = threadIdx.x + 256 * qq;
      int k = i >> 6, n = i & 63;
      Bs[k][n] = Bm[(size_t)(k0 + k) * N + bn + n];
    }
    __syncthreads();
#pragma unroll
    for (int k4 = 0; k4 < BK; k4 += 4) {
      float4 a0 = *(const float4*)&As[ty * 4 + 0][k4];
      float4 a1 = *(const float4*)&As[ty * 4 + 1][k4];
      float4 a2 = *(const float4*)&As[ty * 4 + 2][k4];
      float4 a3 = *(const float4*)&As[ty * 4 + 3][k4];
      float4 b0 = *(const float4*)&Bs[k4 + 0][tx * 4];
      float4 b1 = *(const float4*)&Bs[k4 + 1][tx * 4];
      float4 b2 = *(const float4*)&Bs[k4 + 2][tx * 4];
      float4 b3 = *(const float4*)&Bs[k4 + 3][tx * 4];
#define ROWI(AI)                                          \
      acc[AI][0] = fmaf(a##AI.x, b0.x, acc[AI][0]);       \
      acc[AI][1] = fmaf(a##AI.x, b0.y, acc[AI][1]);       \
      acc[AI][2] = fmaf(a##AI.x, b0.z, acc[AI][2]);       \
      acc[AI][3] = fmaf(a##AI.x, b0.w, acc[AI][3]);       \
      acc[AI][0] = fmaf(a##AI.y, b1.x, acc[AI][0]);       \
      acc[AI][1] = fmaf(a##AI.y, b1.y, acc[AI][1]);       \
      acc[AI][2] = fmaf(a##AI.y, b1.z, acc[AI][2]);       \
      acc[AI][3] = fmaf(a##AI.y, b1.w, acc[AI][3]);       \
      acc[AI][0] = fmaf(a##AI.z, b2.x, acc[AI][0]);       \
      acc[AI][1] = fmaf(a##AI.z, b2.y, acc[AI][1]);       \
      acc[AI][2] = fmaf(a##AI.z, b2.z, acc[AI][2]);       \
      acc[AI][3] = fmaf(a##AI.z, b2.w, acc[AI][3]);       \
      acc[AI][0] = fmaf(a##AI.w, b3.x, acc[AI][0]);       \
      acc[AI][1] = fmaf(a##AI.w, b3.y, acc[AI][1]);       \
      acc[AI][2] = fmaf(a##AI.w, b3.z, acc[AI][2]);       \
      acc[AI][3] = fmaf(a##AI.w, b3.w, acc[AI][3]);
      ROWI(0) ROWI(1) ROWI(2) ROWI(3)
#undef ROWI
    }
    __syncthreads();
  }

  float4 bias4 = *(const float4*)&bias[bn + tx * 4];
#pragma unroll
  for (int i = 0; i < 4; ++i) {
    int m = bm + ty * 4 + i;
    float4 v;
    v.x = acc[i][0] + bias4.x;
    v.y = acc[i][1] + bias4.y;
    v.z = acc[i][2] + bias4.z;
    v.w = acc[i][3] + bias4.w;
    if (resid) {
      float4 r = *(const float4*)&resid[(size_t)m * N + bn + tx * 4];
      v.x += r.x; v.y += r.y; v.z += r.z; v.w += r.w;
    }
    *(float4*)&C[(size_t)m * N + bn + tx * 4] = v;
  }
}

// ---------------------------------------------------------------------------
// v12: the triangular solve is PRECOMPUTED as an explicit inverse.
// All scan variants (v6/v9/v11) pinned at 205-208us / VALUBusy 51%: the
// per-chunk serial solve blocks cross-phase pipelining. Chunk math:
//   d_t = f_t.w_c - f_t[j];  e = (I+L)^{-1} d,  L[t][s] = LR*(f_t.f_s), s<t
//   pred_t = e_t + f_t[j];   w <- w - LR * F^T e
// gram_inv computes M = (I+L)^{-1} per (b,chunk) by forward substitution
// (parallel over 256 blocks) and stores M^T. The scan chunk is then 4
// parallel phases with NO serial recurrence: P0 reduces (independent),
// e = M.d (32 independent fma with readlane broadcasts), preds store,
// acc = F^T e from REGISTER-held rows (launch_bounds(256,1) frees VGPRs).
// Only w carries chunk-to-chunk (4 FMAs).
// ---------------------------------------------------------------------------

template <int CTRL, int RM>
__device__ __forceinline__ float dpp_sum(float v) {
  int moved = __builtin_amdgcn_update_dpp(0, __float_as_int(v), CTRL, RM, 0xF, false);
  return v + __int_as_float(moved);
}

__device__ __forceinline__ float rdlane(float v, int l) {
  return __int_as_float(__builtin_amdgcn_readlane(__float_as_int(v), l));
}

__device__ __forceinline__ void async_copy16(const float* g, float* l) {
  __builtin_amdgcn_global_load_lds(
      (const __attribute__((address_space(1))) unsigned int*)g,
      (__attribute__((address_space(3))) unsigned int*)l, 16, 0, 0);
}

constexpr int RCH = 32;        // rows per chunk
constexpr int NCH = Sc / RCH;  // 64 chunks

// MTg[bc][s*32+t] = M[t][s], M = (I + L)^{-1}, L[t][s] = LR*dot(f_t,f_s) s<t
__global__ __launch_bounds__(256) void gram_inv(const float* __restrict__ feat,
                                                float* __restrict__ MTg) {
  const int bc = blockIdx.x;  // 0..B*NCH-1
  __shared__ float Fl[32 * 260];
  __shared__ float Gl[32 * 32];
  __shared__ float Ml[32 * 32];
  const float* src = feat + (size_t)bc * RCH * Dsc;
  for (int i = threadIdx.x; i < 32 * 256; i += 256) {
    int r = i >> 8, cc = i & 255;
    Fl[r * 260 + cc] = src[i];
  }
  __syncthreads();
#pragma unroll
  for (int k2 = 0; k2 < 4; ++k2) {
    int idx = threadIdx.x + (k2 << 8);
    int t = idx >> 5, s = idx & 31;
    float sum = 0.f;
    if (s < t) {
      const float4* ft = (const float4*)&Fl[t * 260];
      const float4* fs = (const float4*)&Fl[s * 260];
#pragma unroll
      for (int i = 0; i < 64; ++i) {
        float4 a = ft[i], b = fs[i];
        sum = fmaf(a.x, b.x, sum); sum = fmaf(a.y, b.y, sum);
        sum = fmaf(a.z, b.z, sum); sum = fmaf(a.w, b.w, sum);
      }
      sum *= LR;
    }
    Gl[idx] = sum;  // L[t][s] (strict lower), 0 elsewhere
  }
  __syncthreads();
  // Forward substitution, column s per lane: M[t][s] = ind(t==s) - sum_{u<t}
  // L[t][u] M[u][s].  (Upper stays 0 automatically.)
  if (threadIdx.x < 32) {
    const int s = threadIdx.x;
    for (int t = 0; t < 32; ++t) {
      float sum = 0.f;
      for (int u = 0; u < t; ++u)
        sum = fmaf(Gl[t * 32 + u], Ml[u * 32 + s], sum);  // Gl bcast, Ml vec
      Ml[t * 32 + s] = ((t == s) ? 1.f : 0.f) - sum;
    }
  }
  __syncthreads();
  float* dst = MTg + (size_t)bc * 1024;
#pragma unroll
  for (int k2 = 0; k2 < 4; ++k2) {
    int idx = threadIdx.x + (k2 << 8);
    int s = idx >> 5, t = idx & 31;
    dst[idx] = Ml[t * 32 + s];  // transposed store
  }
}

// X-macro row lists
#define ROWS_A(X) X(0) X(1) X(2) X(3) X(4) X(5) X(6) X(7)
#define ROWS_B(X) X(8) X(9) X(10) X(11) X(12) X(13) X(14) X(15)
#define ROWS_C(X) X(16) X(17) X(18) X(19) X(20) X(21) X(22) X(23)
#define ROWS_D(X) X(24) X(25) X(26) X(27) X(28) X(29) X(30) X(31)
#define ROWS_ALL(X) ROWS_A(X) ROWS_B(X) ROWS_C(X) ROWS_D(X)

__global__ __launch_bounds__(256, 1) void ttt_scan(
    const float* __restrict__ feat, const float* __restrict__ MTg,
    float* __restrict__ preds) {
  const int lane = threadIdx.x & 63;
  const int wave = threadIdx.x >> 6;
  const int lm = lane & 31;

  // XCD-locality swizzle (verified: FETCH 32.8 -> 8.2 MB).
  const int bi  = blockIdx.x;                    // 0..255
  const int xcd = bi & 7;
  const int b   = xcd >> 1;                      // 0..3
  const int q   = ((bi >> 3) << 1) | (xcd & 1);  // 0..63
  const int j   = (q << 2) | wave;               // 0..255

  __shared__ float ldsF[2][RCH * Dsc];  // 64 KB
  __shared__ float ldsM[2][1024];       // 8 KB

  const float* fb0 = feat + (size_t)b * Sc * Dsc;
  const float* Mg  = MTg + (size_t)b * NCH * 1024;
  float* pb0 = preds + (size_t)b * Sc * Dsc + j;

// 9 async ops per wave per stage: 8 feat rows (16B/lane) + 1/4 of MT chunk.
#define STAGE(BUF, C0)                                                    \
  {                                                                       \
    _Pragma("unroll")                                                     \
    for (int r_ = 0; r_ < 8; ++r_) {                                      \
      const int row_ = (wave << 3) | r_;                                  \
      async_copy16(fb0 + (size_t)((C0) * RCH + row_) * Dsc + (lane << 2), \
                   &ldsF[BUF][row_ * Dsc]);                               \
    }                                                                     \
    async_copy16(Mg + (size_t)(C0) * 1024 + (wave << 8) + (lane << 2),    \
                 &ldsM[BUF][wave << 8]);                                  \
  }

#define DECLF(R) float Fa##R##_0, Fa##R##_1, Fa##R##_2, Fa##R##_3, FJ##R;

#define LOADF(R)                           \
  Fa##R##_0 = pF[(R) * 256 + lane];        \
  Fa##R##_1 = pF[(R) * 256 + lane + 64];   \
  Fa##R##_2 = pF[(R) * 256 + lane + 128];  \
  Fa##R##_3 = pF[(R) * 256 + lane + 192];  \
  FJ##R     = pF[(R) * 256 + j];

// P0 for row R: dot(f_R, w) -> DPP reduce -> d_R gathered to lane R.
// All 32 chains independent (no shared serial register).
#define P0C(R)                                                                 \
  {                                                                            \
    float dd = fmaf(Fa##R##_1, w1, Fa##R##_0 * w0) +                           \
               fmaf(Fa##R##_3, w3, Fa##R##_2 * w2);                            \
    dd = dpp_sum<0x111, 0xF>(dd);                                              \
    dd = dpp_sum<0x112, 0xF>(dd);                                              \
    dd = dpp_sum<0x114, 0xF>(dd);                                              \
    dd = dpp_sum<0x118, 0xF>(dd);                                              \
    dd = dpp_sum<0x142, 0xA>(dd);                                              \
    dd = dpp_sum<0x143, 0xC>(dd);                                              \
    float p0_ = rdlane(dd, 63);                                                \
    float dsc_ = p0_ - FJ##R;                                                  \
    v_d   = (lane == (R)) ? dsc_ : v_d;                                        \
    v_fja = (lane == (R)) ? FJ##R : v_fja;                                     \
  }

// Matvec step s: e += M^T[s][lane] * d[s]  (independent; 4 partial chains).
#define MV(S, EK)                                  \
  {                                                \
    float ms_ = pM[(S) * 32 + lm];                 \
    float dx_ = rdlane(v_d, (S));                  \
    e##EK = fmaf(ms_, dx_, e##EK);                 \
  }

// acc += e_t * f_t (rows held in registers; 4 independent chains).
#define ACCT(R)                                    \
  {                                                \
    float et_ = rdlane(v_e, (R));                  \
    acc0 = fmaf(et_, Fa##R##_0, acc0);             \
    acc1 = fmaf(et_, Fa##R##_1, acc1);             \
    acc2 = fmaf(et_, Fa##R##_2, acc2);             \
    acc3 = fmaf(et_, Fa##R##_3, acc3);             \
  }

  // Prologue: stage chunks 0,1; wait for chunk 0 (chunk 1's 9 may remain).
  STAGE(0, 0);
  STAGE(1, 1);
  asm volatile("s_waitcnt vmcnt(9)" ::: "memory");
  __builtin_amdgcn_s_barrier();
  __builtin_amdgcn_sched_barrier(0);

  float w0 = 0.f, w1 = 0.f, w2 = 0.f, w3 = 0.f;

#pragma unroll 1
  for (int c = 0; c < NCH; ++c) {
    const int cb = c & 1;
    const float* pF = &ldsF[cb][0];
    const float* pM = &ldsM[cb][0];

    ROWS_ALL(DECLF)
    float v_d = 0.f, v_fja = 0.f;
    float e0 = 0.f, e1 = 0.f, e2 = 0.f, e3 = 0.f;
    float acc0 = 0.f, acc1 = 0.f, acc2 = 0.f, acc3 = 0.f;

    // Phase 1: loads pipelined one 8-row group ahead of P0 compute.
    ROWS_A(LOADF)
    ROWS_B(LOADF)
    __builtin_amdgcn_sched_barrier(0);
    ROWS_C(LOADF)
    ROWS_A(P0C)
    __builtin_amdgcn_sched_barrier(0);
    ROWS_D(LOADF)
    ROWS_B(P0C)
    __builtin_amdgcn_sched_barrier(0);
    ROWS_C(P0C)
    ROWS_D(P0C)

    // Phase 2: e = M d (no serial recurrence).
    MV(0, 0)  MV(1, 1)  MV(2, 2)  MV(3, 3)
    MV(4, 0)  MV(5, 1)  MV(6, 2)  MV(7, 3)
    MV(8, 0)  MV(9, 1)  MV(10, 2) MV(11, 3)
    MV(12, 0) MV(13, 1) MV(14, 2) MV(15, 3)
    MV(16, 0) MV(17, 1) MV(18, 2) MV(19, 3)
    MV(20, 0) MV(21, 1) MV(22, 2) MV(23, 3)
    MV(24, 0) MV(25, 1) MV(26, 2) MV(27, 3)
    MV(28, 0) MV(29, 1) MV(30, 2) MV(31, 3)
    float v_e = (e0 + e1) + (e2 + e3);

    // Phase 3: preds: p_t = e_t + f_t[j]  (lane t).
    if (lane < 32) pb0[(size_t)(c * RCH + lane) * Dsc] = v_e + v_fja;

    // Phase 4: acc = F^T e from register-held rows; one W update per chunk.
    ROWS_ALL(ACCT)
    w0 = fmaf(-LR, acc0, w0); w1 = fmaf(-LR, acc1, w1);
    w2 = fmaf(-LR, acc2, w2); w3 = fmaf(-LR, acc3, w3);

    // Handoff (proven): barrier -> stage c+2 over buf cb -> counted vmcnt(9)
    // -> barrier.
    __builtin_amdgcn_s_barrier();
    if (c + 2 < NCH) {
      STAGE(cb, c + 2);
      asm volatile("s_waitcnt vmcnt(9)" ::: "memory");
    } else {
      asm volatile("s_waitcnt vmcnt(0)" ::: "memory");
    }
    __builtin_amdgcn_s_barrier();
    __builtin_amdgcn_sched_barrier(0);
  }
#undef ACCT
#undef MV
#undef P0C
#undef LOADF
#undef DECLF
#undef STAGE
}

extern "C" void kernel_launch(void* const* d_in, const int* in_sizes, int n_in,
                              void* d_out, int out_size, void* d_ws, size_t ws_size,
                              hipStream_t stream) {
  const float* x  = (const float*)d_in[0];  // (B,S,D)
  const float* Wd = (const float*)d_in[1];  // (D,Ds)
  const float* bd = (const float*)d_in[2];  // (Ds)
  const float* Wu = (const float*)d_in[3];  // (Ds,D)
  const float* bu = (const float*)d_in[4];  // (D)
  float* out = (float*)d_out;               // (B,S,D)

  float* feat  = (float*)d_ws;                        // B*S*Ds f32 = 8 MB
  float* preds = feat + (size_t)Bc * Sc * Dsc;        // 8 MB
  float* MTg   = preds + (size_t)Bc * Sc * Dsc;       // B*NCH*1024 f32 = 1 MB

  const int M = Bc * Sc;  // 8192
  dim3 blk(256);

  // feat = x @ W_down + b_down   (M=8192, N=256, K=1024)
  gemm_bias<<<dim3(M / 64, Dsc / 64), blk, 0, stream>>>(
      x, Wd, bd, nullptr, feat, M, Dsc, Dc);

  // per-chunk M = (I+L)^{-1} (parallel; Gram + forward substitution)
  gram_inv<<<dim3(Bc * NCH), blk, 0, stream>>>(feat, MTg);

  // chunked scan -> preds (no serial solve inside)
  ttt_scan<<<dim3(Bc * Dsc / 4), blk, 0, stream>>>(feat, MTg, preds);

  // out = preds @ W_up + b_up + x   (M=8192, N=1024, K=256)
  gemm_bias<<<dim3(M / 64, Dc / 64), blk, 0, stream>>>(
      preds, Wu, bu, x, out, M, Dc, Dsc);
}

// Round 12
// 330.337 us; speedup vs baseline: 1.0942x; 1.0942x over previous
//
#include <hip/hip_runtime.h>

#define LR 0.01f

// Problem constants (from reference setup_inputs): B=4, S=2048, D=1024, Ds=256
constexpr int Bc  = 4;
constexpr int Sc  = 2048;
constexpr int Dc  = 1024;
constexpr int Dsc = 256;

// ---------------------------------------------------------------------------
// Tiled fp32 GEMM (v10, verified): A-tile transposed in LDS, float4 reads,
// float4 epilogue.
// ---------------------------------------------------------------------------
__global__ __launch_bounds__(256) void gemm_bias(
    const float* __restrict__ A, const float* __restrict__ Bm,
    const float* __restrict__ bias, const float* __restrict__ resid,
    float* __restrict__ C, int M, int N, int K) {
  constexpr int BM = 64, BN = 64, BK = 16;
  __shared__ float As[BM][BK + 4];
  __shared__ float Bs[BK][BN + 4];

  const int bm = blockIdx.x * BM;
  const int bn = blockIdx.y * BN;
  const int tx = threadIdx.x & 15;
  const int ty = threadIdx.x >> 4;

  float acc[4][4] = {};

  for (int k0 = 0; k0 < K; k0 += BK) {
#pragma unroll
    for (int qq = 0; qq < 4; ++qq) {
      int m = ty + 16 * qq;
      As[m][tx] = A[(size_t)(bm + m) * K + k0 + tx];
    }
#pragma unroll
    for (int qq = 0; qq < 4; ++qq) {
      int i = threadIdx.x + 256 * qq;
      int k = i >> 6, n = i & 63;
      Bs[k][n] = Bm[(size_t)(k0 + k) * N + bn + n];
    }
    __syncthreads();
#pragma unroll
    for (int k4 = 0; k4 < BK; k4 += 4) {
      float4 a0 = *(const float4*)&As[ty * 4 + 0][k4];
      float4 a1 = *(const float4*)&As[ty * 4 + 1][k4];
      float4 a2 = *(const float4*)&As[ty * 4 + 2][k4];
      float4 a3 = *(const float4*)&As[ty * 4 + 3][k4];
      float4 b0 = *(const float4*)&Bs[k4 + 0][tx * 4];
      float4 b1 = *(const float4*)&Bs[k4 + 1][tx * 4];
      float4 b2 = *(const float4*)&Bs[k4 + 2][tx * 4];
      float4 b3 = *(const float4*)&Bs[k4 + 3][tx * 4];
#define ROWI(AI)                                          \
      acc[AI][0] = fmaf(a##AI.x, b0.x, acc[AI][0]);       \
      acc[AI][1] = fmaf(a##AI.x, b0.y, acc[AI][1]);       \
      acc[AI][2] = fmaf(a##AI.x, b0.z, acc[AI][2]);       \
      acc[AI][3] = fmaf(a##AI.x, b0.w, acc[AI][3]);       \
      acc[AI][0] = fmaf(a##AI.y, b1.x, acc[AI][0]);       \
      acc[AI][1] = fmaf(a##AI.y, b1.y, acc[AI][1]);       \
      acc[AI][2] = fmaf(a##AI.y, b1.z, acc[AI][2]);       \
      acc[AI][3] = fmaf(a##AI.y, b1.w, acc[AI][3]);       \
      acc[AI][0] = fmaf(a##AI.z, b2.x, acc[AI][0]);       \
      acc[AI][1] = fmaf(a##AI.z, b2.y, acc[AI][1]);       \
      acc[AI][2] = fmaf(a##AI.z, b2.z, acc[AI][2]);       \
      acc[AI][3] = fmaf(a##AI.z, b2.w, acc[AI][3]);       \
      acc[AI][0] = fmaf(a##AI.w, b3.x, acc[AI][0]);       \
      acc[AI][1] = fmaf(a##AI.w, b3.y, acc[AI][1]);       \
      acc[AI][2] = fmaf(a##AI.w, b3.z, acc[AI][2]);       \
      acc[AI][3] = fmaf(a##AI.w, b3.w, acc[AI][3]);
      ROWI(0) ROWI(1) ROWI(2) ROWI(3)
#undef ROWI
    }
    __syncthreads();
  }

  float4 bias4 = *(const float4*)&bias[bn + tx * 4];
#pragma unroll
  for (int i = 0; i < 4; ++i) {
    int m = bm + ty * 4 + i;
    float4 v;
    v.x = acc[i][0] + bias4.x;
    v.y = acc[i][1] + bias4.y;
    v.z = acc[i][2] + bias4.z;
    v.w = acc[i][3] + bias4.w;
    if (resid) {
      float4 r = *(const float4*)&resid[(size_t)m * N + bn + tx * 4];
      v.x += r.x; v.y += r.y; v.z += r.z; v.w += r.w;
    }
    *(float4*)&C[(size_t)m * N + bn + tx * 4] = v;
  }
}

// ---------------------------------------------------------------------------
// v13 scan: v12's parallel chunk math (precomputed M=(I+L)^{-1}; passed),
// with LDS traffic cut 3x. v12 post-mortem: 195 LDS instrs/wave/chunk on the
// CU-shared LDS pipe (4 waves) was the invariant bottleneck (VALUBusy 42%,
// all compute-structure variants pinned ~205-230us). Changes:
//  - F rows: lane l holds f[4l..4l+3]; ONE ds_read_b128 per row (32/chunk vs
//    128 b32). w/acc relayout to match (math identical).
//  - FJ column: ONE strided ds_read (lane t reads ldsF[t*256+j]; 32-way
//    conflict ~70cyc) replaces 32 broadcast reads + 64 cmp/cndmask; d becomes
//    32 uniform scalars -> MV needs no readlane.
// Per-wave LDS per chunk: 66 instrs (32 b128 + 1 FJ + 32 M + store).
// ---------------------------------------------------------------------------

template <int CTRL, int RM>
__device__ __forceinline__ float dpp_sum(float v) {
  int moved = __builtin_amdgcn_update_dpp(0, __float_as_int(v), CTRL, RM, 0xF, false);
  return v + __int_as_float(moved);
}

__device__ __forceinline__ float rdlane(float v, int l) {
  return __int_as_float(__builtin_amdgcn_readlane(__float_as_int(v), l));
}

__device__ __forceinline__ void async_copy16(const float* g, float* l) {
  __builtin_amdgcn_global_load_lds(
      (const __attribute__((address_space(1))) unsigned int*)g,
      (__attribute__((address_space(3))) unsigned int*)l, 16, 0, 0);
}

constexpr int RCH = 32;        // rows per chunk
constexpr int NCH = Sc / RCH;  // 64 chunks

// MTg[bc][s*32+t] = M[t][s], M = (I + L)^{-1}, L[t][s] = LR*dot(f_t,f_s) s<t
__global__ __launch_bounds__(256) void gram_inv(const float* __restrict__ feat,
                                                float* __restrict__ MTg) {
  const int bc = blockIdx.x;  // 0..B*NCH-1
  __shared__ float Fl[32 * 260];
  __shared__ float Gl[32 * 32];
  __shared__ float Ml[32 * 32];
  const float* src = feat + (size_t)bc * RCH * Dsc;
  for (int i = threadIdx.x; i < 32 * 256; i += 256) {
    int r = i >> 8, cc = i & 255;
    Fl[r * 260 + cc] = src[i];
  }
  __syncthreads();
#pragma unroll
  for (int k2 = 0; k2 < 4; ++k2) {
    int idx = threadIdx.x + (k2 << 8);
    int t = idx >> 5, s = idx & 31;
    float sum = 0.f;
    if (s < t) {
      const float4* ft = (const float4*)&Fl[t * 260];
      const float4* fs = (const float4*)&Fl[s * 260];
#pragma unroll
      for (int i = 0; i < 64; ++i) {
        float4 a = ft[i], b = fs[i];
        sum = fmaf(a.x, b.x, sum); sum = fmaf(a.y, b.y, sum);
        sum = fmaf(a.z, b.z, sum); sum = fmaf(a.w, b.w, sum);
      }
      sum *= LR;
    }
    Gl[idx] = sum;  // L[t][s] (strict lower), 0 elsewhere
  }
  __syncthreads();
  // Forward substitution, column s per lane: M[t][s] = ind(t==s) - sum_{u<t}
  // L[t][u] M[u][s].
  if (threadIdx.x < 32) {
    const int s = threadIdx.x;
    for (int t = 0; t < 32; ++t) {
      float sum = 0.f;
      for (int u = 0; u < t; ++u)
        sum = fmaf(Gl[t * 32 + u], Ml[u * 32 + s], sum);
      Ml[t * 32 + s] = ((t == s) ? 1.f : 0.f) - sum;
    }
  }
  __syncthreads();
  float* dst = MTg + (size_t)bc * 1024;
#pragma unroll
  for (int k2 = 0; k2 < 4; ++k2) {
    int idx = threadIdx.x + (k2 << 8);
    int s = idx >> 5, t = idx & 31;
    dst[idx] = Ml[t * 32 + s];  // transposed store
  }
}

// X-macro row lists
#define ROWS_A(X) X(0) X(1) X(2) X(3) X(4) X(5) X(6) X(7)
#define ROWS_B(X) X(8) X(9) X(10) X(11) X(12) X(13) X(14) X(15)
#define ROWS_C(X) X(16) X(17) X(18) X(19) X(20) X(21) X(22) X(23)
#define ROWS_D(X) X(24) X(25) X(26) X(27) X(28) X(29) X(30) X(31)
#define ROWS_ALL(X) ROWS_A(X) ROWS_B(X) ROWS_C(X) ROWS_D(X)

__global__ __launch_bounds__(256, 1) void ttt_scan(
    const float* __restrict__ feat, const float* __restrict__ MTg,
    float* __restrict__ preds) {
  const int lane = threadIdx.x & 63;
  const int wave = threadIdx.x >> 6;
  const int lm = lane & 31;

  // XCD-locality swizzle (verified: FETCH 32.8 -> 8.2 MB).
  const int bi  = blockIdx.x;                    // 0..255
  const int xcd = bi & 7;
  const int b   = xcd >> 1;                      // 0..3
  const int q   = ((bi >> 3) << 1) | (xcd & 1);  // 0..63
  const int j   = (q << 2) | wave;               // 0..255

  __shared__ float ldsF[2][RCH * Dsc];  // 64 KB
  __shared__ float ldsM[2][1024];       // 8 KB

  const float* fb0 = feat + (size_t)b * Sc * Dsc;
  const float* Mg  = MTg + (size_t)b * NCH * 1024;
  float* pb0 = preds + (size_t)b * Sc * Dsc + j;

#define STAGE(BUF, C0)                                                    \
  {                                                                       \
    _Pragma("unroll")                                                     \
    for (int r_ = 0; r_ < 8; ++r_) {                                      \
      const int row_ = (wave << 3) | r_;                                  \
      async_copy16(fb0 + (size_t)((C0) * RCH + row_) * Dsc + (lane << 2), \
                   &ldsF[BUF][row_ * Dsc]);                               \
    }                                                                     \
    async_copy16(Mg + (size_t)(C0) * 1024 + (wave << 8) + (lane << 2),    \
                 &ldsM[BUF][wave << 8]);                                  \
  }

#define DECLF(R) float4 F4_##R;
#define DECLD(R) float dsc_##R;

// One b128 per row: lane l holds f_R[4l..4l+3].
#define LOADF(R) F4_##R = *(const float4*)&pF[(R) * 256 + (lane << 2)];

// P0 for row R: dot(f_R, w) -> DPP reduce -> uniform d_R = p0 - f_R[j].
#define P0C(R)                                                                 \
  {                                                                            \
    float dd = fmaf(F4_##R.y, w4y, F4_##R.x * w4x) +                           \
               fmaf(F4_##R.w, w4w, F4_##R.z * w4z);                            \
    dd = dpp_sum<0x111, 0xF>(dd);                                              \
    dd = dpp_sum<0x112, 0xF>(dd);                                              \
    dd = dpp_sum<0x114, 0xF>(dd);                                              \
    dd = dpp_sum<0x118, 0xF>(dd);                                              \
    dd = dpp_sum<0x142, 0xA>(dd);                                              \
    dd = dpp_sum<0x143, 0xC>(dd);                                              \
    float p0_ = rdlane(dd, 63);                                                \
    float fj_ = rdlane(v_fjcol, (R));                                          \
    dsc_##R = p0_ - fj_;                                                       \
  }

// Matvec step s: e += M^T[s][lane] * d_s  (d_s uniform; no readlane).
#define MV(S, EK) e##EK = fmaf(pM[(S) * 32 + lm], dsc_##S, e##EK);

// acc += e_t * f_t (register-held rows; 4 independent chains).
#define ACCT(R)                                    \
  {                                                \
    float et_ = rdlane(v_e, (R));                  \
    accx = fmaf(et_, F4_##R.x, accx);              \
    accy = fmaf(et_, F4_##R.y, accy);              \
    accz = fmaf(et_, F4_##R.z, accz);              \
    accw = fmaf(et_, F4_##R.w, accw);              \
  }

  // Prologue: stage chunks 0,1; wait for chunk 0 (chunk 1's 9 may remain).
  STAGE(0, 0);
  STAGE(1, 1);
  asm volatile("s_waitcnt vmcnt(9)" ::: "memory");
  __builtin_amdgcn_s_barrier();
  __builtin_amdgcn_sched_barrier(0);

  float w4x = 0.f, w4y = 0.f, w4z = 0.f, w4w = 0.f;

#pragma unroll 1
  for (int c = 0; c < NCH; ++c) {
    const int cb = c & 1;
    const float* pF = &ldsF[cb][0];
    const float* pM = &ldsM[cb][0];

    ROWS_ALL(DECLF)
    ROWS_ALL(DECLD)
    float e0 = 0.f, e1 = 0.f, e2 = 0.f, e3 = 0.f;
    float accx = 0.f, accy = 0.f, accz = 0.f, accw = 0.f;

    // FJ column, one instruction: lane t -> f_t[j] (32-way conflict, ~70cyc,
    // issued early so latency hides under the b128 row loads).
    float v_fjcol = pF[lm * 256 + j];

    // Phase 1: loads one 8-row group ahead of P0 compute.
    ROWS_A(LOADF)
    ROWS_B(LOADF)
    __builtin_amdgcn_sched_barrier(0);
    ROWS_C(LOADF)
    ROWS_A(P0C)
    __builtin_amdgcn_sched_barrier(0);
    ROWS_D(LOADF)
    ROWS_B(P0C)
    __builtin_amdgcn_sched_barrier(0);
    ROWS_C(P0C)
    ROWS_D(P0C)

    // Phase 2: e = M d (d uniform scalars; 4 independent partial chains).
    MV(0, 0)  MV(1, 1)  MV(2, 2)  MV(3, 3)
    MV(4, 0)  MV(5, 1)  MV(6, 2)  MV(7, 3)
    MV(8, 0)  MV(9, 1)  MV(10, 2) MV(11, 3)
    MV(12, 0) MV(13, 1) MV(14, 2) MV(15, 3)
    MV(16, 0) MV(17, 1) MV(18, 2) MV(19, 3)
    MV(20, 0) MV(21, 1) MV(22, 2) MV(23, 3)
    MV(24, 0) MV(25, 1) MV(26, 2) MV(27, 3)
    MV(28, 0) MV(29, 1) MV(30, 2) MV(31, 3)
    float v_e = (e0 + e1) + (e2 + e3);

    // Phase 3: preds: p_t = e_t + f_t[j]  (lane t).
    if (lane < 32) pb0[(size_t)(c * RCH + lane) * Dsc] = v_e + v_fjcol;

    // Phase 4: acc = F^T e from register rows; one W update per chunk.
    ROWS_ALL(ACCT)
    w4x = fmaf(-LR, accx, w4x); w4y = fmaf(-LR, accy, w4y);
    w4z = fmaf(-LR, accz, w4z); w4w = fmaf(-LR, accw, w4w);

    // Handoff (proven): barrier -> stage c+2 over buf cb -> counted vmcnt(9)
    // -> barrier.
    __builtin_amdgcn_s_barrier();
    if (c + 2 < NCH) {
      STAGE(cb, c + 2);
      asm volatile("s_waitcnt vmcnt(9)" ::: "memory");
    } else {
      asm volatile("s_waitcnt vmcnt(0)" ::: "memory");
    }
    __builtin_amdgcn_s_barrier();
    __builtin_amdgcn_sched_barrier(0);
  }
#undef ACCT
#undef MV
#undef P0C
#undef LOADF
#undef DECLD
#undef DECLF
#undef STAGE
}

extern "C" void kernel_launch(void* const* d_in, const int* in_sizes, int n_in,
                              void* d_out, int out_size, void* d_ws, size_t ws_size,
                              hipStream_t stream) {
  const float* x  = (const float*)d_in[0];  // (B,S,D)
  const float* Wd = (const float*)d_in[1];  // (D,Ds)
  const float* bd = (const float*)d_in[2];  // (Ds)
  const float* Wu = (const float*)d_in[3];  // (Ds,D)
  const float* bu = (const float*)d_in[4];  // (D)
  float* out = (float*)d_out;               // (B,S,D)

  float* feat  = (float*)d_ws;                        // B*S*Ds f32 = 8 MB
  float* preds = feat + (size_t)Bc * Sc * Dsc;        // 8 MB
  float* MTg   = preds + (size_t)Bc * Sc * Dsc;       // B*NCH*1024 f32 = 1 MB

  const int M = Bc * Sc;  // 8192
  dim3 blk(256);

  // feat = x @ W_down + b_down   (M=8192, N=256, K=1024)
  gemm_bias<<<dim3(M / 64, Dsc / 64), blk, 0, stream>>>(
      x, Wd, bd, nullptr, feat, M, Dsc, Dc);

  // per-chunk M = (I+L)^{-1} (parallel; Gram + forward substitution)
  gram_inv<<<dim3(Bc * NCH), blk, 0, stream>>>(feat, MTg);

  // chunked scan -> preds (no serial solve inside)
  ttt_scan<<<dim3(Bc * Dsc / 4), blk, 0, stream>>>(feat, MTg, preds);

  // out = preds @ W_up + b_up + x   (M=8192, N=1024, K=256)
  gemm_bias<<<dim3(M / 64, Dc / 64), blk, 0, stream>>>(
      preds, Wu, bu, x, out, M, Dc, Dsc);
}